// Round 16
// baseline (503.627 us; speedup 1.0000x reference)
//
#include <hip/hip_runtime.h>
#include <hip/hip_bf16.h>

// Problem constants
#define L1C 513
#define EMBC 64
#define VC 6
#define BC 128
#define NCOLS (L1C * VC)                  // 3078
#define NTC 64                            // n-columns per block tile
#define NTILES ((NCOLS + NTC - 1) / NTC)  // 49
#define CSC 13                            // s per chunk
#define NCHUNK ((L1C + CSC - 1) / CSC)    // 40

#define XELEMS ((size_t)L1C * BC * EMBC)
#define XBYTES (XELEMS * 2)               // 8,404,992
#define OUTELEMS ((size_t)BC * NCOLS)     // 393,984
#define PARTBYTES (OUTELEMS * 2)          // bf16 partials per chunk

typedef __attribute__((ext_vector_type(8))) short short8;
typedef __attribute__((ext_vector_type(4))) float f32x4;

__device__ __forceinline__ unsigned int pack_bf16x2(float a, float b) {
    __hip_bfloat16 ha = __float2bfloat16(a);
    __hip_bfloat16 hb = __float2bfloat16(b);
    unsigned short ua, ub;
    __builtin_memcpy(&ua, &ha, 2);
    __builtin_memcpy(&ub, &hb, 2);
    return (unsigned int)ua | ((unsigned int)ub << 16);
}

__device__ __forceinline__ unsigned short bf16bits(float a) {
    __hip_bfloat16 h = __float2bfloat16(a);
    unsigned short u;
    __builtin_memcpy(&u, &h, 2);
    return u;
}

// out[b][v][t] = bias[t][v]   (atomic-fallback path only)
__global__ void init_out_kernel(float* __restrict__ out, const float* __restrict__ bias) {
    int i = blockIdx.x * 256 + threadIdx.x;
    if (i >= (int)OUTELEMS) return;
    int r = i % NCOLS;
    int v = r / L1C;
    int t = r - v * L1C;
    out[i] = bias[t * VC + v];
}

// X[s][b][w] = bf16(emb[src[b,s], w]), linear layout
__global__ void build_x_kernel(const int* __restrict__ src, const float* __restrict__ emb,
                               unsigned short* __restrict__ X) {
    const int s = blockIdx.x;
    const int b = threadIdx.x >> 1;
    const int half = threadIdx.x & 1;
    const int tok = src[b * L1C + s];
    const float2* e = (const float2*)(emb + tok * EMBC + half * 32);
    unsigned int* row = (unsigned int*)(X + ((size_t)s * BC + b) * EMBC) + half * 16;
#pragma unroll
    for (int i = 0; i < 16; ++i) {
        float2 f = e[i];
        row[i] = pack_bf16x2(f.x, f.y);
    }
}

// Per (n-tile, s-chunk) block: C[128 x 64] = sum_{s in chunk, s>=t} X_s(128x64) @ W_s(64x64)
// r15 structure. DIAGNOSTIC: the s-loop runs `reps` times (accumulating; epilogue
// scales by 1/reps, exact for reps=8) so the dispatch exceeds the harness fills
// and surfaces full rocprof counters. Output identical to reps=1 (ulp-level).
template <bool PARTIAL>
__global__ __launch_bounds__(256, 4) void gemm_tril_kernel(
    const float* __restrict__ Wt, const unsigned short* __restrict__ X,
    void* __restrict__ outp, int CS, int reps) {
    // bijective XCD grouping over 49 tiles: q=6, r=1 (m204 form)
    const int xb = blockIdx.x;
    const int xcd = xb & 7;
    const int pos = xb >> 3;
    const int tile = ((xcd == 0) ? 0 : (7 + (xcd - 1) * 6)) + pos;

    const int chunk = blockIdx.y;
    const int n0 = tile * NTC;
    const int s0 = chunk * CS;
    const int sEnd = min(s0 + CS, L1C);
    const int sBeg = max(s0, n0 / VC);
    if (sBeg >= sEnd) return;  // dead block; reduce skips these chunks

    __shared__ __align__(16) unsigned short Blds[2][NTC * EMBC];  // 2 x 8KB

    const int tid = threadIdx.x;
    const int wid = tid >> 6;
    const int lane = tid & 63;
    const int l15 = lane & 15;
    const int h = lane >> 4;

    const int n = n0 + lane;
    const int tcol = n / VC;  // pad columns (n>=NCOLS) -> tcol>=513 -> always masked
    const size_t nsafe = (n < NCOLS) ? (size_t)n : (size_t)(NCOLS - 1);
    const int wrow0 = wid * 16;

    f32x4 acc[2][4];
#pragma unroll
    for (int i = 0; i < 2; ++i)
#pragma unroll
        for (int j = 0; j < 4; ++j) acc[i][j] = f32x4{0.f, 0.f, 0.f, 0.f};

// Raw barrier: drain LDS ops only; global loads stay in flight.
#define SYNCB()                                                \
    {                                                          \
        __builtin_amdgcn_sched_barrier(0);                     \
        asm volatile("s_waitcnt lgkmcnt(0)" ::: "memory");     \
        __builtin_amdgcn_s_barrier();                          \
        __builtin_amdgcn_sched_barrier(0);                     \
    }

#define ISSUEW(ss, farr)                                                         \
    {                                                                            \
        const float* wb_ = Wt + ((size_t)(ss) * EMBC + wrow0) * NCOLS + nsafe;   \
        _Pragma("unroll") for (int u_ = 0; u_ < 16; ++u_)                        \
            farr[u_] = wb_[(size_t)u_ * NCOLS];                                  \
    }

// 8B-granular swizzle: logical byte col c of row r stored at c ^ ((r&15)<<3)
#define PACKW(ss, farr, buf)                                                     \
    {                                                                            \
        const bool act_ = (tcol <= (ss));                                        \
        char* dr_ = (char*)Blds[buf] + lane * 128;                               \
        const int sw_ = (lane & 15) << 3;                                        \
        _Pragma("unroll") for (int u_ = 0; u_ < 4; ++u_) {                       \
            float g0 = act_ ? farr[u_ * 4 + 0] : 0.f;                            \
            float g1 = act_ ? farr[u_ * 4 + 1] : 0.f;                            \
            float g2 = act_ ? farr[u_ * 4 + 2] : 0.f;                            \
            float g3 = act_ ? farr[u_ * 4 + 3] : 0.f;                            \
            uint2 pk_ = make_uint2(pack_bf16x2(g0, g1), pack_bf16x2(g2, g3));    \
            *(uint2*)(dr_ + ((wid * 32 + u_ * 8) ^ sw_)) = pk_;                  \
        }                                                                        \
    }

#define ISSUEA(ss, aarr)                                                             \
    {                                                                                \
        const int scl_ = ((ss) < L1C) ? (ss) : (L1C - 1);                            \
        const unsigned short* xr_ = X + (size_t)scl_ * (BC * EMBC);                  \
        aarr[0] = *(const short8*)(xr_ + (wid * 32 + l15) * EMBC + h * 8);           \
        aarr[1] = *(const short8*)(xr_ + (wid * 32 + l15) * EMBC + 32 + h * 8);      \
        aarr[2] = *(const short8*)(xr_ + (wid * 32 + 16 + l15) * EMBC + h * 8);      \
        aarr[3] = *(const short8*)(xr_ + (wid * 32 + 16 + l15) * EMBC + 32 + h * 8); \
    }

// B-frag read: two ds_read_b64 per fragment (8B swizzle)
#define MFMASTEP(aarr, buf)                                                                          \
    {                                                                                                \
        const int sw_ = l15 << 3;                                                                    \
        _Pragma("unroll") for (int kk_ = 0; kk_ < 2; ++kk_) {                                        \
            _Pragma("unroll") for (int nt_ = 0; nt_ < 4; ++nt_) {                                    \
                const char* rb_ = (const char*)Blds[buf] + (nt_ * 16 + l15) * 128;                   \
                const int c0_ = (kk_ * 64 + h * 16) ^ sw_;                                           \
                short8 bb_;                                                                          \
                __builtin_memcpy(&bb_, rb_ + c0_, 8);                                                \
                __builtin_memcpy((char*)&bb_ + 8, rb_ + (c0_ ^ 8), 8);                               \
                acc[0][nt_] = __builtin_amdgcn_mfma_f32_16x16x32_bf16(aarr[kk_], bb_, acc[0][nt_], 0, 0, 0);     \
                acc[1][nt_] = __builtin_amdgcn_mfma_f32_16x16x32_bf16(aarr[2 + kk_], bb_, acc[1][nt_], 0, 0, 0); \
            }                                                                                        \
        }                                                                                            \
    }

    for (int rep = 0; rep < reps; ++rep) {
        float fW0[16], fW1[16];
        short8 aC[4];
        // prologue: stage B(sBeg); issue A(sBeg) then W(sBeg+1)
        ISSUEW(sBeg, fW1);
        PACKW(sBeg, fW1, 0);
        ISSUEA(sBeg, aC);
        if (sBeg + 1 < sEnd) ISSUEW(sBeg + 1, fW0);
        SYNCB();

        int s = sBeg, cur = 0;
        while (true) {
            // even iter: W(s+2) first; MFMA consumes aC=A(s) (retires W(s+1));
            // refresh aC <- A(s+1) after consumption; pack fW0 (no wait).
            if (s + 2 < sEnd) ISSUEW(s + 2, fW1);
            MFMASTEP(aC, cur);
            if (s + 1 < sEnd) {
                ISSUEA(s + 1, aC);
                PACKW(s + 1, fW0, cur ^ 1);
            }
            SYNCB();
            cur ^= 1;
            if (++s >= sEnd) break;

            // odd iter: consume fW1
            if (s + 2 < sEnd) ISSUEW(s + 2, fW0);
            MFMASTEP(aC, cur);
            if (s + 1 < sEnd) {
                ISSUEA(s + 1, aC);
                PACKW(s + 1, fW1, cur ^ 1);
            }
            SYNCB();
            cur ^= 1;
            if (++s >= sEnd) break;
        }
    }

    const float sc = 1.0f / (float)reps;  // exact for reps = power of 2

    // epilogue — C/D layout (verified): col = l15 (n), row-in-16 = h*4 + reg
#pragma unroll
    for (int nt = 0; nt < 4; ++nt) {
        const int nn = n0 + nt * 16 + l15;
        if (nn >= NCOLS) continue;
        if (PARTIAL) {
            unsigned short* dst = (unsigned short*)outp + (size_t)chunk * OUTELEMS;
#pragma unroll
            for (int ms = 0; ms < 2; ++ms)
#pragma unroll
                for (int r = 0; r < 4; ++r) {
                    const int bi = wid * 32 + ms * 16 + h * 4 + r;
                    dst[(size_t)bi * NCOLS + nn] = bf16bits(acc[ms][nt][r] * sc);
                }
        } else {
            float* dst = (float*)outp;
            const int t = nn / VC;
            const int v = nn - t * VC;
            const size_t obase = (size_t)v * L1C + t;
#pragma unroll
            for (int ms = 0; ms < 2; ++ms)
#pragma unroll
                for (int r = 0; r < 4; ++r) {
                    const int bi = wid * 32 + ms * 16 + h * 4 + r;
                    atomicAdd(dst + (size_t)bi * NCOLS + obase, acc[ms][nt][r] * sc);
                }
        }
    }
#undef SYNCB
#undef ISSUEW
#undef PACKW
#undef ISSUEA
#undef MFMASTEP
}

// out[b][v][t] = bias[n] + sum_{c>=cfirst(tile(n))} bf16 partial[c][b][n],  n = t*6+v
__global__ void reduce_kernel(const unsigned short* __restrict__ partial,
                              const float* __restrict__ bias,
                              float* __restrict__ out, int nchunks, int CS) {
    int i4 = blockIdx.x * 256 + threadIdx.x;
    if (i4 >= (int)(OUTELEMS / 4)) return;
    const size_t base = (size_t)i4 * 4;
    float sum[4];
    int cf[4];
    int cmin = 1 << 30;
#pragma unroll
    for (int j = 0; j < 4; ++j) {
        int idx = (int)base + j;
        int nn = idx % NCOLS;
        sum[j] = bias[nn];
        int tl = nn >> 6;              // tile = nn / NTC (NTC=64)
        int tmin = (tl << 6) / VC;     // first live s for this tile
        cf[j] = tmin / CS;             // first live chunk (matches gemm's sBeg rule)
        cmin = min(cmin, cf[j]);
    }
    for (int c = cmin; c < nchunks; ++c) {
        const ushort4 p = *(const ushort4*)(partial + (size_t)c * OUTELEMS + base);
        unsigned int u0 = (unsigned int)p.x << 16, u1 = (unsigned int)p.y << 16;
        unsigned int u2 = (unsigned int)p.z << 16, u3 = (unsigned int)p.w << 16;
        float f0, f1, f2, f3;
        __builtin_memcpy(&f0, &u0, 4);
        __builtin_memcpy(&f1, &u1, 4);
        __builtin_memcpy(&f2, &u2, 4);
        __builtin_memcpy(&f3, &u3, 4);
        if (c >= cf[0]) sum[0] += f0;
        if (c >= cf[1]) sum[1] += f1;
        if (c >= cf[2]) sum[2] += f2;
        if (c >= cf[3]) sum[3] += f3;
    }
#pragma unroll
    for (int j = 0; j < 4; ++j) {
        int idx = (int)base + j;
        int b = idx / NCOLS;
        int nn = idx - b * NCOLS;
        int t = nn / VC;
        int v = nn - t * VC;
        out[(size_t)b * NCOLS + (size_t)v * L1C + t] = sum[j];
    }
}

extern "C" void kernel_launch(void* const* d_in, const int* in_sizes, int n_in,
                              void* d_out, int out_size, void* d_ws, size_t ws_size,
                              hipStream_t stream) {
    const int* src = (const int*)d_in[0];
    const float* emb = (const float*)d_in[1];
    const float* wt = (const float*)d_in[2];
    const float* bias = (const float*)d_in[3];
    float* out = (float*)d_out;
    unsigned short* X = (unsigned short*)d_ws;

    build_x_kernel<<<L1C, 256, 0, stream>>>(src, emb, X);

    if (ws_size >= XBYTES + (size_t)NCHUNK * PARTBYTES) {
        unsigned short* partial = (unsigned short*)((char*)d_ws + XBYTES);
        dim3 grid(NTILES, NCHUNK);   // blockIdx.x is XCD-swizzled inside the kernel
        // DIAGNOSTIC round: reps=8 so the gemm dispatch outlasts the harness's
        // ws-poison fills and surfaces full rocprof counters. Output unchanged.
        gemm_tril_kernel<true><<<grid, 256, 0, stream>>>(wt, X, (void*)partial, CSC, 8);
        reduce_kernel<<<(int)((OUTELEMS / 4 + 255) / 256), 256, 0, stream>>>(partial, bias, out, NCHUNK, CSC);
    } else if (ws_size >= XBYTES + 2 * PARTBYTES) {
        int nchunks = (int)((ws_size - XBYTES) / PARTBYTES);
        if (nchunks > NCHUNK) nchunks = NCHUNK;
        int CS = (L1C + nchunks - 1) / nchunks;
        nchunks = (L1C + CS - 1) / CS;
        unsigned short* partial = (unsigned short*)((char*)d_ws + XBYTES);
        dim3 grid(NTILES, nchunks);
        gemm_tril_kernel<true><<<grid, 256, 0, stream>>>(wt, X, (void*)partial, CS, 1);
        reduce_kernel<<<(int)((OUTELEMS / 4 + 255) / 256), 256, 0, stream>>>(partial, bias, out, nchunks, CS);
    } else {
        init_out_kernel<<<(int)((OUTELEMS + 255) / 256), 256, 0, stream>>>(out, bias);
        dim3 grid(NTILES, 17);
        gemm_tril_kernel<false><<<grid, 256, 0, stream>>>(wt, X, (void*)out, 31, 1);
    }
}

// Round 17
// 94.742 us; speedup vs baseline: 5.3158x; 5.3158x over previous
//
#include <hip/hip_runtime.h>
#include <hip/hip_bf16.h>

// Problem constants
#define L1C 513
#define EMBC 64
#define VC 6
#define BC 128
#define NCOLS (L1C * VC)                  // 3078
#define NTC 128                           // n-columns per block tile (512B W spans)
#define NTILES ((NCOLS + NTC - 1) / NTC)  // 25
#define CSC 13                            // s per chunk: ~520 live blocks ~= 2/CU (one generation)
#define NCHUNK ((L1C + CSC - 1) / CSC)    // 40

#define XELEMS ((size_t)L1C * BC * EMBC)
#define XBYTES (XELEMS * 2)               // 8,404,992
#define OUTELEMS ((size_t)BC * NCOLS)     // 393,984
#define PARTBYTES (OUTELEMS * 2)          // bf16 partials per chunk

typedef __attribute__((ext_vector_type(8))) short short8;
typedef __attribute__((ext_vector_type(4))) float f32x4;

__device__ __forceinline__ unsigned int pack_bf16x2(float a, float b) {
    __hip_bfloat16 ha = __float2bfloat16(a);
    __hip_bfloat16 hb = __float2bfloat16(b);
    unsigned short ua, ub;
    __builtin_memcpy(&ua, &ha, 2);
    __builtin_memcpy(&ub, &hb, 2);
    return (unsigned int)ua | ((unsigned int)ub << 16);
}

__device__ __forceinline__ unsigned short bf16bits(float a) {
    __hip_bfloat16 h = __float2bfloat16(a);
    unsigned short u;
    __builtin_memcpy(&u, &h, 2);
    return u;
}

// per-col LDS swizzle slot: injective over c&15 within a read group (cols nt*16+l15)
// AND over c>>2 within a write group (cols 4k+j, j fixed) -> both sides conflict-free.
__device__ __forceinline__ int swz_slot(int c) {
    return (c & 12) | ((((c >> 1) ^ (c >> 4)) & 1) << 1) | ((c ^ (c >> 5)) & 1);
}

// out[b][v][t] = bias[t][v]   (atomic-fallback path only)
__global__ void init_out_kernel(float* __restrict__ out, const float* __restrict__ bias) {
    int i = blockIdx.x * 256 + threadIdx.x;
    if (i >= (int)OUTELEMS) return;
    int r = i % NCOLS;
    int v = r / L1C;
    int t = r - v * L1C;
    out[i] = bias[t * VC + v];
}

// X[s][b][w] = bf16(emb[src[b,s], w]), linear layout
__global__ void build_x_kernel(const int* __restrict__ src, const float* __restrict__ emb,
                               unsigned short* __restrict__ X) {
    const int s = blockIdx.x;
    const int b = threadIdx.x >> 1;
    const int half = threadIdx.x & 1;
    const int tok = src[b * L1C + s];
    const float2* e = (const float2*)(emb + tok * EMBC + half * 32);
    unsigned int* row = (unsigned int*)(X + ((size_t)s * BC + b) * EMBC) + half * 16;
#pragma unroll
    for (int i = 0; i < 16; ++i) {
        float2 f = e[i];
        row[i] = pack_bf16x2(f.x, f.y);
    }
}

// Per (n-tile, s-chunk) block: C[128 x 128] = sum_{s in chunk, s>=t} X_s(128x64) @ W_s(64x128)
// W read as 512B contiguous spans (32 lanes x 16B per row); conflict-free LDS swizzle both
// sides; 2-deep W register pipeline with FIFO-aware order; SYNCB barriers.
template <bool PARTIAL>
__global__ __launch_bounds__(256, 2) void gemm_tril_kernel(
    const float* __restrict__ Wt, const unsigned short* __restrict__ X,
    void* __restrict__ outp, int CS) {
    // bijective XCD grouping over 25 tiles: q=3, r=1 (m204 form)
    const int xb = blockIdx.x;
    const int xcd = xb & 7;
    const int pos = xb >> 3;
    const int tile = ((xcd == 0) ? 0 : (4 + (xcd - 1) * 3)) + pos;

    const int chunk = blockIdx.y;
    const int n0 = tile * NTC;
    const int s0 = chunk * CS;
    const int sEnd = min(s0 + CS, L1C);
    const int sBeg = max(s0, n0 / VC);
    if (sBeg >= sEnd) return;  // dead block; reduce skips these chunks

    __shared__ __align__(16) unsigned short Blds[2][NTC * EMBC];  // 2 x 16KB

    const int tid = threadIdx.x;
    const int wid = tid >> 6;
    const int lane = tid & 63;
    const int l15 = lane & 15;
    const int h = lane >> 4;

    // --- W staging role: 4 adjacent cols (c0..c0+3), 8 consecutive w-rows
    const int k31 = lane & 31;
    const int c0 = 4 * k31;                       // col group within tile
    const int wr0 = wid * 16 + (lane >> 5) * 8;   // w-row base (8 rows)
    int tc[4];
#pragma unroll
    for (int j = 0; j < 4; ++j) tc[j] = (n0 + c0 + j) / VC;  // >=513 for pad cols -> masked

    f32x4 acc[2][8];
#pragma unroll
    for (int i = 0; i < 2; ++i)
#pragma unroll
        for (int j = 0; j < 8; ++j) acc[i][j] = f32x4{0.f, 0.f, 0.f, 0.f};

// Raw barrier: drain LDS ops only; global loads stay in flight.
#define SYNCB()                                                \
    {                                                          \
        __builtin_amdgcn_sched_barrier(0);                     \
        asm volatile("s_waitcnt lgkmcnt(0)" ::: "memory");     \
        __builtin_amdgcn_s_barrier();                          \
        __builtin_amdgcn_sched_barrier(0);                     \
    }

// 8 rows x 16B contiguous per thread; wave spans 512B per row pair
#define ISSUEW(ss, farr)                                                            \
    {                                                                               \
        const float* wb_ = Wt + (size_t)((ss) * EMBC + wr0) * NCOLS;                \
        if (n0 + c0 + 4 <= NCOLS) {                                                 \
            _Pragma("unroll") for (int i_ = 0; i_ < 8; ++i_)                        \
                __builtin_memcpy(&farr[i_][0], wb_ + (size_t)i_ * NCOLS + n0 + c0, 16); \
        } else {                                                                    \
            _Pragma("unroll") for (int i_ = 0; i_ < 8; ++i_) {                      \
                _Pragma("unroll") for (int j_ = 0; j_ < 4; ++j_) {                  \
                    const int cj_ = (n0 + c0 + j_ < NCOLS) ? (n0 + c0 + j_) : (NCOLS - 1); \
                    farr[i_][j_] = wb_[(size_t)i_ * NCOLS + cj_];                   \
                }                                                                   \
            }                                                                       \
        }                                                                           \
    }

#define PACKW(ss, farr, buf)                                                        \
    {                                                                               \
        _Pragma("unroll") for (int j_ = 0; j_ < 4; ++j_) {                          \
            const int c_ = c0 + j_;                                                 \
            const bool act_ = (tc[j_] <= (ss));                                     \
            const int fsw_ = swz_slot(c_) << 3;                                     \
            char* dr_ = (char*)Blds[buf] + c_ * 128;                                \
            _Pragma("unroll") for (int u_ = 0; u_ < 2; ++u_) {                      \
                float g0 = act_ ? farr[4 * u_ + 0][j_] : 0.f;                       \
                float g1 = act_ ? farr[4 * u_ + 1][j_] : 0.f;                       \
                float g2 = act_ ? farr[4 * u_ + 2][j_] : 0.f;                       \
                float g3 = act_ ? farr[4 * u_ + 3][j_] : 0.f;                       \
                uint2 pk_ = make_uint2(pack_bf16x2(g0, g1), pack_bf16x2(g2, g3));   \
                *(uint2*)(dr_ + ((2 * wr0 + 8 * u_) ^ fsw_)) = pk_;                 \
            }                                                                       \
        }                                                                           \
    }

#define ISSUEA(ss, aarr)                                                             \
    {                                                                                \
        const int scl_ = ((ss) < L1C) ? (ss) : (L1C - 1);                            \
        const unsigned short* xr_ = X + (size_t)scl_ * (BC * EMBC);                  \
        aarr[0] = *(const short8*)(xr_ + (wid * 32 + l15) * EMBC + h * 8);           \
        aarr[1] = *(const short8*)(xr_ + (wid * 32 + l15) * EMBC + 32 + h * 8);      \
        aarr[2] = *(const short8*)(xr_ + (wid * 32 + 16 + l15) * EMBC + h * 8);      \
        aarr[3] = *(const short8*)(xr_ + (wid * 32 + 16 + l15) * EMBC + 32 + h * 8); \
    }

// B-frag read: two ds_read_b64 per fragment; conflict-free via swz_slot
#define MFMASTEP(aarr, buf)                                                                          \
    {                                                                                                \
        _Pragma("unroll") for (int kk_ = 0; kk_ < 2; ++kk_) {                                        \
            _Pragma("unroll") for (int nt_ = 0; nt_ < 8; ++nt_) {                                    \
                const int c_ = nt_ * 16 + l15;                                                       \
                const int fsw_ = swz_slot(c_) << 3;                                                  \
                const char* rb_ = (const char*)Blds[buf] + c_ * 128;                                 \
                const int o1_ = (kk_ * 64 + h * 16) ^ fsw_;                                          \
                short8 bb_;                                                                          \
                __builtin_memcpy(&bb_, rb_ + o1_, 8);                                                \
                __builtin_memcpy((char*)&bb_ + 8, rb_ + (o1_ ^ 8), 8);                               \
                acc[0][nt_] = __builtin_amdgcn_mfma_f32_16x16x32_bf16(aarr[kk_], bb_, acc[0][nt_], 0, 0, 0);     \
                acc[1][nt_] = __builtin_amdgcn_mfma_f32_16x16x32_bf16(aarr[2 + kk_], bb_, acc[1][nt_], 0, 0, 0); \
            }                                                                                        \
        }                                                                                            \
    }

    {
        float fW0[8][4], fW1[8][4];
        short8 aC[4];
        // prologue: stage B(sBeg); A(sBeg); W(sBeg+1) in flight
        ISSUEW(sBeg, fW1);
        PACKW(sBeg, fW1, 0);
        ISSUEA(sBeg, aC);
        if (sBeg + 1 < sEnd) ISSUEW(sBeg + 1, fW0);
        SYNCB();

        int s = sBeg, cur = 0;
        while (true) {
            // W(s+2) first; MFMA consumes aC=A(s) (its vmcnt-wait retires W(s+1));
            // refresh aC <- A(s+1) after consumption; pack fW0 without waiting.
            if (s + 2 < sEnd) ISSUEW(s + 2, fW1);
            MFMASTEP(aC, cur);
            if (s + 1 < sEnd) {
                ISSUEA(s + 1, aC);
                PACKW(s + 1, fW0, cur ^ 1);
            }
            SYNCB();
            cur ^= 1;
            if (++s >= sEnd) break;

            if (s + 2 < sEnd) ISSUEW(s + 2, fW0);
            MFMASTEP(aC, cur);
            if (s + 1 < sEnd) {
                ISSUEA(s + 1, aC);
                PACKW(s + 1, fW1, cur ^ 1);
            }
            SYNCB();
            cur ^= 1;
            if (++s >= sEnd) break;
        }
    }

    // epilogue — C/D layout (verified): col = l15 (n), row-in-16 = h*4 + reg
#pragma unroll
    for (int nt = 0; nt < 8; ++nt) {
        const int nn = n0 + nt * 16 + l15;
        if (nn >= NCOLS) continue;
        if (PARTIAL) {
            unsigned short* dst = (unsigned short*)outp + (size_t)chunk * OUTELEMS;
#pragma unroll
            for (int ms = 0; ms < 2; ++ms)
#pragma unroll
                for (int r = 0; r < 4; ++r) {
                    const int bi = wid * 32 + ms * 16 + h * 4 + r;
                    dst[(size_t)bi * NCOLS + nn] = bf16bits(acc[ms][nt][r]);
                }
        } else {
            float* dst = (float*)outp;
            const int t = nn / VC;
            const int v = nn - t * VC;
            const size_t obase = (size_t)v * L1C + t;
#pragma unroll
            for (int ms = 0; ms < 2; ++ms)
#pragma unroll
                for (int r = 0; r < 4; ++r) {
                    const int bi = wid * 32 + ms * 16 + h * 4 + r;
                    atomicAdd(dst + (size_t)bi * NCOLS + obase, acc[ms][nt][r]);
                }
        }
    }
#undef SYNCB
#undef ISSUEW
#undef PACKW
#undef ISSUEA
#undef MFMASTEP
}

// out[b][v][t] = bias[n] + sum_{c>=cfirst(tile(n))} bf16 partial[c][b][n],  n = t*6+v
__global__ void reduce_kernel(const unsigned short* __restrict__ partial,
                              const float* __restrict__ bias,
                              float* __restrict__ out, int nchunks, int CS) {
    int i4 = blockIdx.x * 256 + threadIdx.x;
    if (i4 >= (int)(OUTELEMS / 4)) return;
    const size_t base = (size_t)i4 * 4;
    float sum[4];
    int cf[4];
    int cmin = 1 << 30;
#pragma unroll
    for (int j = 0; j < 4; ++j) {
        int idx = (int)base + j;
        int nn = idx % NCOLS;
        sum[j] = bias[nn];
        int tl = nn >> 7;              // tile = nn / NTC (NTC=128)
        int tmin = (tl << 7) / VC;     // first live s for this tile
        cf[j] = tmin / CS;             // first live chunk (matches gemm's sBeg rule)
        cmin = min(cmin, cf[j]);
    }
    for (int c = cmin; c < nchunks; ++c) {
        const ushort4 p = *(const ushort4*)(partial + (size_t)c * OUTELEMS + base);
        unsigned int u0 = (unsigned int)p.x << 16, u1 = (unsigned int)p.y << 16;
        unsigned int u2 = (unsigned int)p.z << 16, u3 = (unsigned int)p.w << 16;
        float f0, f1, f2, f3;
        __builtin_memcpy(&f0, &u0, 4);
        __builtin_memcpy(&f1, &u1, 4);
        __builtin_memcpy(&f2, &u2, 4);
        __builtin_memcpy(&f3, &u3, 4);
        if (c >= cf[0]) sum[0] += f0;
        if (c >= cf[1]) sum[1] += f1;
        if (c >= cf[2]) sum[2] += f2;
        if (c >= cf[3]) sum[3] += f3;
    }
#pragma unroll
    for (int j = 0; j < 4; ++j) {
        int idx = (int)base + j;
        int b = idx / NCOLS;
        int nn = idx - b * NCOLS;
        int t = nn / VC;
        int v = nn - t * VC;
        out[(size_t)b * NCOLS + (size_t)v * L1C + t] = sum[j];
    }
}

extern "C" void kernel_launch(void* const* d_in, const int* in_sizes, int n_in,
                              void* d_out, int out_size, void* d_ws, size_t ws_size,
                              hipStream_t stream) {
    const int* src = (const int*)d_in[0];
    const float* emb = (const float*)d_in[1];
    const float* wt = (const float*)d_in[2];
    const float* bias = (const float*)d_in[3];
    float* out = (float*)d_out;
    unsigned short* X = (unsigned short*)d_ws;

    build_x_kernel<<<L1C, 256, 0, stream>>>(src, emb, X);

    if (ws_size >= XBYTES + (size_t)NCHUNK * PARTBYTES) {
        unsigned short* partial = (unsigned short*)((char*)d_ws + XBYTES);
        dim3 grid(NTILES, NCHUNK);   // blockIdx.x is XCD-swizzled inside the kernel
        gemm_tril_kernel<true><<<grid, 256, 0, stream>>>(wt, X, (void*)partial, CSC);
        reduce_kernel<<<(int)((OUTELEMS / 4 + 255) / 256), 256, 0, stream>>>(partial, bias, out, NCHUNK, CSC);
    } else if (ws_size >= XBYTES + 2 * PARTBYTES) {
        int nchunks = (int)((ws_size - XBYTES) / PARTBYTES);
        if (nchunks > NCHUNK) nchunks = NCHUNK;
        int CS = (L1C + nchunks - 1) / nchunks;
        nchunks = (L1C + CS - 1) / CS;
        unsigned short* partial = (unsigned short*)((char*)d_ws + XBYTES);
        dim3 grid(NTILES, nchunks);
        gemm_tril_kernel<true><<<grid, 256, 0, stream>>>(wt, X, (void*)partial, CS);
        reduce_kernel<<<(int)((OUTELEMS / 4 + 255) / 256), 256, 0, stream>>>(partial, bias, out, nchunks, CS);
    } else {
        init_out_kernel<<<(int)((OUTELEMS + 255) / 256), 256, 0, stream>>>(out, bias);
        dim3 grid(NTILES, 17);
        gemm_tril_kernel<false><<<grid, 256, 0, stream>>>(wt, X, (void*)out, 31);
    }
}

// Round 18
// 83.421 us; speedup vs baseline: 6.0372x; 1.1357x over previous
//
#include <hip/hip_runtime.h>
#include <hip/hip_bf16.h>

// Problem constants
#define L1C 513
#define EMBC 64
#define VC 6
#define BC 128
#define NCOLS (L1C * VC)                  // 3078
#define NTC 64                            // n-columns per block tile
#define NTILES ((NCOLS + NTC - 1) / NTC)  // 49
#define CSC 26                            // s per chunk: ~512 live blocks ~= 2/CU, refetch 7.7%
#define NCHUNK ((L1C + CSC - 1) / CSC)    // 20

#define XELEMS ((size_t)L1C * BC * EMBC)
#define XBYTES (XELEMS * 2)               // 8,404,992
#define OUTELEMS ((size_t)BC * NCOLS)     // 393,984
#define PARTBYTES (OUTELEMS * 2)          // bf16 partials per chunk

typedef __attribute__((ext_vector_type(8))) short short8;
typedef __attribute__((ext_vector_type(4))) float f32x4;

__device__ __forceinline__ unsigned int pack_bf16x2(float a, float b) {
    __hip_bfloat16 ha = __float2bfloat16(a);
    __hip_bfloat16 hb = __float2bfloat16(b);
    unsigned short ua, ub;
    __builtin_memcpy(&ua, &ha, 2);
    __builtin_memcpy(&ub, &hb, 2);
    return (unsigned int)ua | ((unsigned int)ub << 16);
}

__device__ __forceinline__ unsigned short bf16bits(float a) {
    __hip_bfloat16 h = __float2bfloat16(a);
    unsigned short u;
    __builtin_memcpy(&u, &h, 2);
    return u;
}

// out[b][v][t] = bias[t][v]   (atomic-fallback path only)
__global__ void init_out_kernel(float* __restrict__ out, const float* __restrict__ bias) {
    int i = blockIdx.x * 256 + threadIdx.x;
    if (i >= (int)OUTELEMS) return;
    int r = i % NCOLS;
    int v = r / L1C;
    int t = r - v * L1C;
    out[i] = bias[t * VC + v];
}

// X[s][b][w] = bf16(emb[src[b,s], w]), linear layout
__global__ void build_x_kernel(const int* __restrict__ src, const float* __restrict__ emb,
                               unsigned short* __restrict__ X) {
    const int s = blockIdx.x;
    const int b = threadIdx.x >> 1;
    const int half = threadIdx.x & 1;
    const int tok = src[b * L1C + s];
    const float2* e = (const float2*)(emb + tok * EMBC + half * 32);
    unsigned int* row = (unsigned int*)(X + ((size_t)s * BC + b) * EMBC) + half * 16;
#pragma unroll
    for (int i = 0; i < 16; ++i) {
        float2 f = e[i];
        row[i] = pack_bf16x2(f.x, f.y);
    }
}

// Per (n-tile, s-chunk) block: C[128 x 64] = sum_{s in chunk, s>=t} X_s(128x64) @ W_s(64x64)
// r15 structure (best: 81.7us). CS=26 cuts prologue refetch to 7.7%; chunks dispatched
// heavy-first (reverse order) so long blocks start early and light ones backfill.
template <bool PARTIAL>
__global__ __launch_bounds__(256, 4) void gemm_tril_kernel(
    const float* __restrict__ Wt, const unsigned short* __restrict__ X,
    void* __restrict__ outp, int CS, int nchunks) {
    // bijective XCD grouping over 49 tiles: q=6, r=1 (m204 form)
    const int xb = blockIdx.x;
    const int xcd = xb & 7;
    const int pos = xb >> 3;
    const int tile = ((xcd == 0) ? 0 : (7 + (xcd - 1) * 6)) + pos;

    const int chunk = nchunks - 1 - blockIdx.y;  // heavy-first (LPT) dispatch
    const int n0 = tile * NTC;
    const int s0 = chunk * CS;
    const int sEnd = min(s0 + CS, L1C);
    const int sBeg = max(s0, n0 / VC);
    if (sBeg >= sEnd) return;  // dead block; reduce skips these chunks

    __shared__ __align__(16) unsigned short Blds[2][NTC * EMBC];  // 2 x 8KB

    const int tid = threadIdx.x;
    const int wid = tid >> 6;
    const int lane = tid & 63;
    const int l15 = lane & 15;
    const int h = lane >> 4;

    const int n = n0 + lane;
    const int tcol = n / VC;  // pad columns (n>=NCOLS) -> tcol>=513 -> always masked
    const size_t nsafe = (n < NCOLS) ? (size_t)n : (size_t)(NCOLS - 1);
    const int wrow0 = wid * 16;

    f32x4 acc[2][4];
#pragma unroll
    for (int i = 0; i < 2; ++i)
#pragma unroll
        for (int j = 0; j < 4; ++j) acc[i][j] = f32x4{0.f, 0.f, 0.f, 0.f};

// Raw barrier: drain LDS ops only; global loads stay in flight.
#define SYNCB()                                                \
    {                                                          \
        __builtin_amdgcn_sched_barrier(0);                     \
        asm volatile("s_waitcnt lgkmcnt(0)" ::: "memory");     \
        __builtin_amdgcn_s_barrier();                          \
        __builtin_amdgcn_sched_barrier(0);                     \
    }

#define ISSUEW(ss, farr)                                                         \
    {                                                                            \
        const float* wb_ = Wt + ((size_t)(ss) * EMBC + wrow0) * NCOLS + nsafe;   \
        _Pragma("unroll") for (int u_ = 0; u_ < 16; ++u_)                        \
            farr[u_] = wb_[(size_t)u_ * NCOLS];                                  \
    }

// 8B-granular swizzle: logical byte col c of row r stored at c ^ ((r&15)<<3)
#define PACKW(ss, farr, buf)                                                     \
    {                                                                            \
        const bool act_ = (tcol <= (ss));                                        \
        char* dr_ = (char*)Blds[buf] + lane * 128;                               \
        const int sw_ = (lane & 15) << 3;                                        \
        _Pragma("unroll") for (int u_ = 0; u_ < 4; ++u_) {                       \
            float g0 = act_ ? farr[u_ * 4 + 0] : 0.f;                            \
            float g1 = act_ ? farr[u_ * 4 + 1] : 0.f;                            \
            float g2 = act_ ? farr[u_ * 4 + 2] : 0.f;                            \
            float g3 = act_ ? farr[u_ * 4 + 3] : 0.f;                            \
            uint2 pk_ = make_uint2(pack_bf16x2(g0, g1), pack_bf16x2(g2, g3));    \
            *(uint2*)(dr_ + ((wid * 32 + u_ * 8) ^ sw_)) = pk_;                  \
        }                                                                        \
    }

#define ISSUEA(ss, aarr)                                                             \
    {                                                                                \
        const int scl_ = ((ss) < L1C) ? (ss) : (L1C - 1);                            \
        const unsigned short* xr_ = X + (size_t)scl_ * (BC * EMBC);                  \
        aarr[0] = *(const short8*)(xr_ + (wid * 32 + l15) * EMBC + h * 8);           \
        aarr[1] = *(const short8*)(xr_ + (wid * 32 + l15) * EMBC + 32 + h * 8);      \
        aarr[2] = *(const short8*)(xr_ + (wid * 32 + 16 + l15) * EMBC + h * 8);      \
        aarr[3] = *(const short8*)(xr_ + (wid * 32 + 16 + l15) * EMBC + 32 + h * 8); \
    }

// B-frag read: two ds_read_b64 per fragment (8B swizzle)
#define MFMASTEP(aarr, buf)                                                                          \
    {                                                                                                \
        const int sw_ = l15 << 3;                                                                    \
        _Pragma("unroll") for (int kk_ = 0; kk_ < 2; ++kk_) {                                        \
            _Pragma("unroll") for (int nt_ = 0; nt_ < 4; ++nt_) {                                    \
                const char* rb_ = (const char*)Blds[buf] + (nt_ * 16 + l15) * 128;                   \
                const int c0_ = (kk_ * 64 + h * 16) ^ sw_;                                           \
                short8 bb_;                                                                          \
                __builtin_memcpy(&bb_, rb_ + c0_, 8);                                                \
                __builtin_memcpy((char*)&bb_ + 8, rb_ + (c0_ ^ 8), 8);                               \
                acc[0][nt_] = __builtin_amdgcn_mfma_f32_16x16x32_bf16(aarr[kk_], bb_, acc[0][nt_], 0, 0, 0);     \
                acc[1][nt_] = __builtin_amdgcn_mfma_f32_16x16x32_bf16(aarr[2 + kk_], bb_, acc[1][nt_], 0, 0, 0); \
            }                                                                                        \
        }                                                                                            \
    }

    {
        float fW0[16], fW1[16];
        short8 aC[4];
        // prologue: stage B(sBeg); issue A(sBeg) then W(sBeg+1)
        ISSUEW(sBeg, fW1);
        PACKW(sBeg, fW1, 0);
        ISSUEA(sBeg, aC);
        if (sBeg + 1 < sEnd) ISSUEW(sBeg + 1, fW0);
        SYNCB();

        int s = sBeg, cur = 0;
        while (true) {
            // W(s+2) first; MFMA consumes aC=A(s) (its vmcnt-wait retires W(s+1));
            // refresh aC <- A(s+1) after consumption; pack fW0 without waiting.
            if (s + 2 < sEnd) ISSUEW(s + 2, fW1);
            MFMASTEP(aC, cur);
            if (s + 1 < sEnd) {
                ISSUEA(s + 1, aC);
                PACKW(s + 1, fW0, cur ^ 1);
            }
            SYNCB();
            cur ^= 1;
            if (++s >= sEnd) break;

            // odd iter: consume fW1
            if (s + 2 < sEnd) ISSUEW(s + 2, fW0);
            MFMASTEP(aC, cur);
            if (s + 1 < sEnd) {
                ISSUEA(s + 1, aC);
                PACKW(s + 1, fW1, cur ^ 1);
            }
            SYNCB();
            cur ^= 1;
            if (++s >= sEnd) break;
        }
    }

    // epilogue — C/D layout (verified): col = l15 (n), row-in-16 = h*4 + reg
#pragma unroll
    for (int nt = 0; nt < 4; ++nt) {
        const int nn = n0 + nt * 16 + l15;
        if (nn >= NCOLS) continue;
        if (PARTIAL) {
            unsigned short* dst = (unsigned short*)outp + (size_t)chunk * OUTELEMS;
#pragma unroll
            for (int ms = 0; ms < 2; ++ms)
#pragma unroll
                for (int r = 0; r < 4; ++r) {
                    const int bi = wid * 32 + ms * 16 + h * 4 + r;
                    dst[(size_t)bi * NCOLS + nn] = bf16bits(acc[ms][nt][r]);
                }
        } else {
            float* dst = (float*)outp;
            const int t = nn / VC;
            const int v = nn - t * VC;
            const size_t obase = (size_t)v * L1C + t;
#pragma unroll
            for (int ms = 0; ms < 2; ++ms)
#pragma unroll
                for (int r = 0; r < 4; ++r) {
                    const int bi = wid * 32 + ms * 16 + h * 4 + r;
                    atomicAdd(dst + (size_t)bi * NCOLS + obase, acc[ms][nt][r]);
                }
        }
    }
#undef SYNCB
#undef ISSUEW
#undef PACKW
#undef ISSUEA
#undef MFMASTEP
}

// out[b][v][t] = bias[n] + sum_{c>=cfirst(tile(n))} bf16 partial[c][b][n],  n = t*6+v
__global__ void reduce_kernel(const unsigned short* __restrict__ partial,
                              const float* __restrict__ bias,
                              float* __restrict__ out, int nchunks, int CS) {
    int i4 = blockIdx.x * 256 + threadIdx.x;
    if (i4 >= (int)(OUTELEMS / 4)) return;
    const size_t base = (size_t)i4 * 4;
    float sum[4];
    int cf[4];
    int cmin = 1 << 30;
#pragma unroll
    for (int j = 0; j < 4; ++j) {
        int idx = (int)base + j;
        int nn = idx % NCOLS;
        sum[j] = bias[nn];
        int tl = nn >> 6;              // tile = nn / NTC (NTC=64)
        int tmin = (tl << 6) / VC;     // first live s for this tile
        cf[j] = tmin / CS;             // first live chunk (matches gemm's sBeg rule)
        cmin = min(cmin, cf[j]);
    }
    for (int c = cmin; c < nchunks; ++c) {
        const ushort4 p = *(const ushort4*)(partial + (size_t)c * OUTELEMS + base);
        unsigned int u0 = (unsigned int)p.x << 16, u1 = (unsigned int)p.y << 16;
        unsigned int u2 = (unsigned int)p.z << 16, u3 = (unsigned int)p.w << 16;
        float f0, f1, f2, f3;
        __builtin_memcpy(&f0, &u0, 4);
        __builtin_memcpy(&f1, &u1, 4);
        __builtin_memcpy(&f2, &u2, 4);
        __builtin_memcpy(&f3, &u3, 4);
        if (c >= cf[0]) sum[0] += f0;
        if (c >= cf[1]) sum[1] += f1;
        if (c >= cf[2]) sum[2] += f2;
        if (c >= cf[3]) sum[3] += f3;
    }
#pragma unroll
    for (int j = 0; j < 4; ++j) {
        int idx = (int)base + j;
        int b = idx / NCOLS;
        int nn = idx - b * NCOLS;
        int t = nn / VC;
        int v = nn - t * VC;
        out[(size_t)b * NCOLS + (size_t)v * L1C + t] = sum[j];
    }
}

extern "C" void kernel_launch(void* const* d_in, const int* in_sizes, int n_in,
                              void* d_out, int out_size, void* d_ws, size_t ws_size,
                              hipStream_t stream) {
    const int* src = (const int*)d_in[0];
    const float* emb = (const float*)d_in[1];
    const float* wt = (const float*)d_in[2];
    const float* bias = (const float*)d_in[3];
    float* out = (float*)d_out;
    unsigned short* X = (unsigned short*)d_ws;

    build_x_kernel<<<L1C, 256, 0, stream>>>(src, emb, X);

    if (ws_size >= XBYTES + (size_t)NCHUNK * PARTBYTES) {
        unsigned short* partial = (unsigned short*)((char*)d_ws + XBYTES);
        dim3 grid(NTILES, NCHUNK);   // blockIdx.x XCD-swizzled; chunk reversed (heavy-first)
        gemm_tril_kernel<true><<<grid, 256, 0, stream>>>(wt, X, (void*)partial, CSC, NCHUNK);
        reduce_kernel<<<(int)((OUTELEMS / 4 + 255) / 256), 256, 0, stream>>>(partial, bias, out, NCHUNK, CSC);
    } else if (ws_size >= XBYTES + 2 * PARTBYTES) {
        int nchunks = (int)((ws_size - XBYTES) / PARTBYTES);
        if (nchunks > NCHUNK) nchunks = NCHUNK;
        int CS = (L1C + nchunks - 1) / nchunks;
        nchunks = (L1C + CS - 1) / CS;
        unsigned short* partial = (unsigned short*)((char*)d_ws + XBYTES);
        dim3 grid(NTILES, nchunks);
        gemm_tril_kernel<true><<<grid, 256, 0, stream>>>(wt, X, (void*)partial, CS, nchunks);
        reduce_kernel<<<(int)((OUTELEMS / 4 + 255) / 256), 256, 0, stream>>>(partial, bias, out, nchunks, CS);
    } else {
        init_out_kernel<<<(int)((OUTELEMS + 255) / 256), 256, 0, stream>>>(out, bias);
        dim3 grid(NTILES, 17);
        gemm_tril_kernel<false><<<grid, 256, 0, stream>>>(wt, X, (void*)out, 31, 17);
    }
}

// Round 19
// 81.504 us; speedup vs baseline: 6.1792x; 1.0235x over previous
//
#include <hip/hip_runtime.h>
#include <hip/hip_bf16.h>

// Problem constants
#define L1C 513
#define EMBC 64
#define VC 6
#define BC 128
#define NCOLS (L1C * VC)                  // 3078
#define NTC 64                            // n-columns per block tile
#define NTILES ((NCOLS + NTC - 1) / NTC)  // 49
#define CSC 13                            // s per chunk: ~1000 live blocks ~= full 4/CU residency
#define NCHUNK ((L1C + CSC - 1) / CSC)    // 40

#define XELEMS ((size_t)L1C * BC * EMBC)
#define XBYTES (XELEMS * 2)               // 8,404,992
#define OUTELEMS ((size_t)BC * NCOLS)     // 393,984
#define PARTBYTES (OUTELEMS * 2)          // bf16 partials per chunk

typedef __attribute__((ext_vector_type(8))) short short8;
typedef __attribute__((ext_vector_type(4))) float f32x4;

__device__ __forceinline__ unsigned int pack_bf16x2(float a, float b) {
    __hip_bfloat16 ha = __float2bfloat16(a);
    __hip_bfloat16 hb = __float2bfloat16(b);
    unsigned short ua, ub;
    __builtin_memcpy(&ua, &ha, 2);
    __builtin_memcpy(&ub, &hb, 2);
    return (unsigned int)ua | ((unsigned int)ub << 16);
}

__device__ __forceinline__ unsigned short bf16bits(float a) {
    __hip_bfloat16 h = __float2bfloat16(a);
    unsigned short u;
    __builtin_memcpy(&u, &h, 2);
    return u;
}

// out[b][v][t] = bias[t][v]   (atomic-fallback path only)
__global__ void init_out_kernel(float* __restrict__ out, const float* __restrict__ bias) {
    int i = blockIdx.x * 256 + threadIdx.x;
    if (i >= (int)OUTELEMS) return;
    int r = i % NCOLS;
    int v = r / L1C;
    int t = r - v * L1C;
    out[i] = bias[t * VC + v];
}

// X[s][b][w] = bf16(emb[src[b,s], w]), linear layout
__global__ void build_x_kernel(const int* __restrict__ src, const float* __restrict__ emb,
                               unsigned short* __restrict__ X) {
    const int s = blockIdx.x;
    const int b = threadIdx.x >> 1;
    const int half = threadIdx.x & 1;
    const int tok = src[b * L1C + s];
    const float2* e = (const float2*)(emb + tok * EMBC + half * 32);
    unsigned int* row = (unsigned int*)(X + ((size_t)s * BC + b) * EMBC) + half * 16;
#pragma unroll
    for (int i = 0; i < 16; ++i) {
        float2 f = e[i];
        row[i] = pack_bf16x2(f.x, f.y);
    }
}

// Per (n-tile, s-chunk) block: C[128 x 64] = sum_{s in chunk, s>=t} X_s(128x64) @ W_s(64x64)
// Best configuration (r15, 81.7us): register-diet + FIFO-aware reorder (single aC set,
// refreshed AFTER the MFMAs): steady-state issue order ... W(s+1), A(s), W(s+2), A(s+1) ...
// so the MFMA's A(s)-wait retires W(s+1) after one full iteration of flight; PACKW never waits.
// 8B-granular LDS swizzle: bank conflicts measured 0 (r16 PMC). Bytes optimal (202MB live W).
template <bool PARTIAL>
__global__ __launch_bounds__(256, 4) void gemm_tril_kernel(
    const float* __restrict__ Wt, const unsigned short* __restrict__ X,
    void* __restrict__ outp, int CS) {
    // bijective XCD grouping over 49 tiles: q=6, r=1 (m204 form)
    const int xb = blockIdx.x;
    const int xcd = xb & 7;
    const int pos = xb >> 3;
    const int tile = ((xcd == 0) ? 0 : (7 + (xcd - 1) * 6)) + pos;

    const int chunk = blockIdx.y;
    const int n0 = tile * NTC;
    const int s0 = chunk * CS;
    const int sEnd = min(s0 + CS, L1C);
    const int sBeg = max(s0, n0 / VC);
    if (sBeg >= sEnd) return;  // dead block; reduce skips these chunks

    __shared__ __align__(16) unsigned short Blds[2][NTC * EMBC];  // 2 x 8KB

    const int tid = threadIdx.x;
    const int wid = tid >> 6;
    const int lane = tid & 63;
    const int l15 = lane & 15;
    const int h = lane >> 4;

    const int n = n0 + lane;
    const int tcol = n / VC;  // pad columns (n>=NCOLS) -> tcol>=513 -> always masked
    const size_t nsafe = (n < NCOLS) ? (size_t)n : (size_t)(NCOLS - 1);
    const int wrow0 = wid * 16;

    f32x4 acc[2][4];
#pragma unroll
    for (int i = 0; i < 2; ++i)
#pragma unroll
        for (int j = 0; j < 4; ++j) acc[i][j] = f32x4{0.f, 0.f, 0.f, 0.f};

// Raw barrier: drain LDS ops only; global loads stay in flight.
#define SYNCB()                                                \
    {                                                          \
        __builtin_amdgcn_sched_barrier(0);                     \
        asm volatile("s_waitcnt lgkmcnt(0)" ::: "memory");     \
        __builtin_amdgcn_s_barrier();                          \
        __builtin_amdgcn_sched_barrier(0);                     \
    }

#define ISSUEW(ss, farr)                                                         \
    {                                                                            \
        const float* wb_ = Wt + ((size_t)(ss) * EMBC + wrow0) * NCOLS + nsafe;   \
        _Pragma("unroll") for (int u_ = 0; u_ < 16; ++u_)                        \
            farr[u_] = wb_[(size_t)u_ * NCOLS];                                  \
    }

// 8B-granular swizzle: logical byte col c of row r stored at c ^ ((r&15)<<3)
#define PACKW(ss, farr, buf)                                                     \
    {                                                                            \
        const bool act_ = (tcol <= (ss));                                        \
        char* dr_ = (char*)Blds[buf] + lane * 128;                               \
        const int sw_ = (lane & 15) << 3;                                        \
        _Pragma("unroll") for (int u_ = 0; u_ < 4; ++u_) {                       \
            float g0 = act_ ? farr[u_ * 4 + 0] : 0.f;                            \
            float g1 = act_ ? farr[u_ * 4 + 1] : 0.f;                            \
            float g2 = act_ ? farr[u_ * 4 + 2] : 0.f;                            \
            float g3 = act_ ? farr[u_ * 4 + 3] : 0.f;                            \
            uint2 pk_ = make_uint2(pack_bf16x2(g0, g1), pack_bf16x2(g2, g3));    \
            *(uint2*)(dr_ + ((wid * 32 + u_ * 8) ^ sw_)) = pk_;                  \
        }                                                                        \
    }

#define ISSUEA(ss, aarr)                                                             \
    {                                                                                \
        const int scl_ = ((ss) < L1C) ? (ss) : (L1C - 1);                            \
        const unsigned short* xr_ = X + (size_t)scl_ * (BC * EMBC);                  \
        aarr[0] = *(const short8*)(xr_ + (wid * 32 + l15) * EMBC + h * 8);           \
        aarr[1] = *(const short8*)(xr_ + (wid * 32 + l15) * EMBC + 32 + h * 8);      \
        aarr[2] = *(const short8*)(xr_ + (wid * 32 + 16 + l15) * EMBC + h * 8);      \
        aarr[3] = *(const short8*)(xr_ + (wid * 32 + 16 + l15) * EMBC + 32 + h * 8); \
    }

// B-frag read: two ds_read_b64 per fragment (8B swizzle)
#define MFMASTEP(aarr, buf)                                                                          \
    {                                                                                                \
        const int sw_ = l15 << 3;                                                                    \
        _Pragma("unroll") for (int kk_ = 0; kk_ < 2; ++kk_) {                                        \
            _Pragma("unroll") for (int nt_ = 0; nt_ < 4; ++nt_) {                                    \
                const char* rb_ = (const char*)Blds[buf] + (nt_ * 16 + l15) * 128;                   \
                const int c0_ = (kk_ * 64 + h * 16) ^ sw_;                                           \
                short8 bb_;                                                                          \
                __builtin_memcpy(&bb_, rb_ + c0_, 8);                                                \
                __builtin_memcpy((char*)&bb_ + 8, rb_ + (c0_ ^ 8), 8);                               \
                acc[0][nt_] = __builtin_amdgcn_mfma_f32_16x16x32_bf16(aarr[kk_], bb_, acc[0][nt_], 0, 0, 0);     \
                acc[1][nt_] = __builtin_amdgcn_mfma_f32_16x16x32_bf16(aarr[2 + kk_], bb_, acc[1][nt_], 0, 0, 0); \
            }                                                                                        \
        }                                                                                            \
    }

    {
        float fW0[16], fW1[16];
        short8 aC[4];
        // prologue: stage B(sBeg); issue A(sBeg) then W(sBeg+1)
        ISSUEW(sBeg, fW1);
        PACKW(sBeg, fW1, 0);
        ISSUEA(sBeg, aC);
        if (sBeg + 1 < sEnd) ISSUEW(sBeg + 1, fW0);
        SYNCB();

        int s = sBeg, cur = 0;
        while (true) {
            // even iter: W(s+2) first; MFMA consumes aC=A(s) (retires W(s+1));
            // refresh aC <- A(s+1) after consumption; pack fW0 (no wait).
            if (s + 2 < sEnd) ISSUEW(s + 2, fW1);
            MFMASTEP(aC, cur);
            if (s + 1 < sEnd) {
                ISSUEA(s + 1, aC);
                PACKW(s + 1, fW0, cur ^ 1);
            }
            SYNCB();
            cur ^= 1;
            if (++s >= sEnd) break;

            // odd iter: consume fW1
            if (s + 2 < sEnd) ISSUEW(s + 2, fW0);
            MFMASTEP(aC, cur);
            if (s + 1 < sEnd) {
                ISSUEA(s + 1, aC);
                PACKW(s + 1, fW1, cur ^ 1);
            }
            SYNCB();
            cur ^= 1;
            if (++s >= sEnd) break;
        }
    }

    // epilogue — C/D layout (verified): col = l15 (n), row-in-16 = h*4 + reg
#pragma unroll
    for (int nt = 0; nt < 4; ++nt) {
        const int nn = n0 + nt * 16 + l15;
        if (nn >= NCOLS) continue;
        if (PARTIAL) {
            unsigned short* dst = (unsigned short*)outp + (size_t)chunk * OUTELEMS;
#pragma unroll
            for (int ms = 0; ms < 2; ++ms)
#pragma unroll
                for (int r = 0; r < 4; ++r) {
                    const int bi = wid * 32 + ms * 16 + h * 4 + r;
                    dst[(size_t)bi * NCOLS + nn] = bf16bits(acc[ms][nt][r]);
                }
        } else {
            float* dst = (float*)outp;
            const int t = nn / VC;
            const int v = nn - t * VC;
            const size_t obase = (size_t)v * L1C + t;
#pragma unroll
            for (int ms = 0; ms < 2; ++ms)
#pragma unroll
                for (int r = 0; r < 4; ++r) {
                    const int bi = wid * 32 + ms * 16 + h * 4 + r;
                    atomicAdd(dst + (size_t)bi * NCOLS + obase, acc[ms][nt][r]);
                }
        }
    }
#undef SYNCB
#undef ISSUEW
#undef PACKW
#undef ISSUEA
#undef MFMASTEP
}

// out[b][v][t] = bias[n] + sum_{c>=cfirst(tile(n))} bf16 partial[c][b][n],  n = t*6+v
__global__ void reduce_kernel(const unsigned short* __restrict__ partial,
                              const float* __restrict__ bias,
                              float* __restrict__ out, int nchunks, int CS) {
    int i4 = blockIdx.x * 256 + threadIdx.x;
    if (i4 >= (int)(OUTELEMS / 4)) return;
    const size_t base = (size_t)i4 * 4;
    float sum[4];
    int cf[4];
    int cmin = 1 << 30;
#pragma unroll
    for (int j = 0; j < 4; ++j) {
        int idx = (int)base + j;
        int nn = idx % NCOLS;
        sum[j] = bias[nn];
        int tl = nn >> 6;              // tile = nn / NTC (NTC=64)
        int tmin = (tl << 6) / VC;     // first live s for this tile
        cf[j] = tmin / CS;             // first live chunk (matches gemm's sBeg rule)
        cmin = min(cmin, cf[j]);
    }
    for (int c = cmin; c < nchunks; ++c) {
        const ushort4 p = *(const ushort4*)(partial + (size_t)c * OUTELEMS + base);
        unsigned int u0 = (unsigned int)p.x << 16, u1 = (unsigned int)p.y << 16;
        unsigned int u2 = (unsigned int)p.z << 16, u3 = (unsigned int)p.w << 16;
        float f0, f1, f2, f3;
        __builtin_memcpy(&f0, &u0, 4);
        __builtin_memcpy(&f1, &u1, 4);
        __builtin_memcpy(&f2, &u2, 4);
        __builtin_memcpy(&f3, &u3, 4);
        if (c >= cf[0]) sum[0] += f0;
        if (c >= cf[1]) sum[1] += f1;
        if (c >= cf[2]) sum[2] += f2;
        if (c >= cf[3]) sum[3] += f3;
    }
#pragma unroll
    for (int j = 0; j < 4; ++j) {
        int idx = (int)base + j;
        int b = idx / NCOLS;
        int nn = idx - b * NCOLS;
        int t = nn / VC;
        int v = nn - t * VC;
        out[(size_t)b * NCOLS + (size_t)v * L1C + t] = sum[j];
    }
}

extern "C" void kernel_launch(void* const* d_in, const int* in_sizes, int n_in,
                              void* d_out, int out_size, void* d_ws, size_t ws_size,
                              hipStream_t stream) {
    const int* src = (const int*)d_in[0];
    const float* emb = (const float*)d_in[1];
    const float* wt = (const float*)d_in[2];
    const float* bias = (const float*)d_in[3];
    float* out = (float*)d_out;
    unsigned short* X = (unsigned short*)d_ws;

    build_x_kernel<<<L1C, 256, 0, stream>>>(src, emb, X);

    if (ws_size >= XBYTES + (size_t)NCHUNK * PARTBYTES) {
        unsigned short* partial = (unsigned short*)((char*)d_ws + XBYTES);
        dim3 grid(NTILES, NCHUNK);   // blockIdx.x is XCD-swizzled inside the kernel
        gemm_tril_kernel<true><<<grid, 256, 0, stream>>>(wt, X, (void*)partial, CSC);
        reduce_kernel<<<(int)((OUTELEMS / 4 + 255) / 256), 256, 0, stream>>>(partial, bias, out, NCHUNK, CSC);
    } else if (ws_size >= XBYTES + 2 * PARTBYTES) {
        int nchunks = (int)((ws_size - XBYTES) / PARTBYTES);
        if (nchunks > NCHUNK) nchunks = NCHUNK;
        int CS = (L1C + nchunks - 1) / nchunks;
        nchunks = (L1C + CS - 1) / CS;
        unsigned short* partial = (unsigned short*)((char*)d_ws + XBYTES);
        dim3 grid(NTILES, nchunks);
        gemm_tril_kernel<true><<<grid, 256, 0, stream>>>(wt, X, (void*)partial, CS);
        reduce_kernel<<<(int)((OUTELEMS / 4 + 255) / 256), 256, 0, stream>>>(partial, bias, out, nchunks, CS);
    } else {
        init_out_kernel<<<(int)((OUTELEMS + 255) / 256), 256, 0, stream>>>(out, bias);
        dim3 grid(NTILES, 17);
        gemm_tril_kernel<false><<<grid, 256, 0, stream>>>(wt, X, (void*)out, 31);
    }
}